// Round 3
// baseline (4106.240 us; speedup 1.0000x reference)
//
#include <hip/hip_runtime.h>
#include <stdint.h>

#define TN_D 1024
#define TN_F 1024
#define SENT32 0xAAAAAAAAu

__device__ __forceinline__ float dot4(float4 a, float4 b) {
    return a.x * b.x + a.y * b.y + a.z * b.z + a.w * b.w;
}

// ---------------------------------------------------------------------------
// Transpose core[s][i][j] -> coreT[s][j][i], 64x64 tiles, block (16,16).
// ---------------------------------------------------------------------------
__global__ __launch_bounds__(256) void tn_transpose(const float* __restrict__ core,
                                                    float* __restrict__ coreT) {
    __shared__ float tile[64][65];
    const int s = blockIdx.z;
    const size_t base = (size_t)s * TN_D * TN_D;
    const int j0 = blockIdx.x * 64;
    const int i0 = blockIdx.y * 64;
    const int tx = threadIdx.x;  // 0..15 (float4 column)
    const int ty = threadIdx.y;  // 0..15 (row)
#pragma unroll
    for (int r = 0; r < 4; ++r) {
        const int ii = ty + 16 * r;
        const float4 v = *(const float4*)&core[base + (size_t)(i0 + ii) * TN_D + j0 + 4 * tx];
        tile[ii][4 * tx + 0] = v.x;
        tile[ii][4 * tx + 1] = v.y;
        tile[ii][4 * tx + 2] = v.z;
        tile[ii][4 * tx + 3] = v.w;
    }
    __syncthreads();
#pragma unroll
    for (int r = 0; r < 4; ++r) {
        const int jj = ty + 16 * r;
        float4 v;
        v.x = tile[4 * tx + 0][jj];
        v.y = tile[4 * tx + 1][jj];
        v.z = tile[4 * tx + 2][jj];
        v.w = tile[4 * tx + 3][jj];
        *(float4*)&coreT[base + (size_t)(j0 + jj) * TN_D + i0 + 4 * tx] = v;
    }
}

// Spin until 4 dwords at vp are all != sentinel (0xAA poison; true values > 0).
__device__ __forceinline__ float4 poll4(const uint32_t* vp) {
    const unsigned long long* p = (const unsigned long long*)vp;
    unsigned long long a = __hip_atomic_load(p, __ATOMIC_RELAXED, __HIP_MEMORY_SCOPE_AGENT);
    unsigned long long b = __hip_atomic_load(p + 1, __ATOMIC_RELAXED, __HIP_MEMORY_SCOPE_AGENT);
    while ((uint32_t)a == SENT32 || (uint32_t)(a >> 32) == SENT32)
        a = __hip_atomic_load(p, __ATOMIC_RELAXED, __HIP_MEMORY_SCOPE_AGENT);
    while ((uint32_t)b == SENT32 || (uint32_t)(b >> 32) == SENT32)
        b = __hip_atomic_load(p + 1, __ATOMIC_RELAXED, __HIP_MEMORY_SCOPE_AGENT);
    return make_float4(__uint_as_float((uint32_t)a), __uint_as_float((uint32_t)(a >> 32)),
                       __uint_as_float((uint32_t)b), __uint_as_float((uint32_t)(b >> 32)));
}

// ---------------------------------------------------------------------------
// Persistent chain kernel. 256 blocks x 512 threads.
// Waves 0..3: compute (own column j = 4*blk + w); waves 4..7: loaders.
// Loaders pipeline matrix columns 2 steps ahead into triple-buffered LDS, so
// their vmcnt drain never sits in front of the compute waves' poll loads.
// One __syncthreads() per step. Data-flow sync across blocks via 0xAA
// sentinel values in vg (relaxed agent-scope atomics, no fences needed).
// ---------------------------------------------------------------------------
template <bool TR>
__global__ __launch_bounds__(512, 1) void tn_chain(const int* __restrict__ x,
                                                   const float* __restrict__ mat,
                                                   const float* __restrict__ left,
                                                   const float* __restrict__ right,
                                                   float* __restrict__ vg,
                                                   float* __restrict__ out) {
    __shared__ float4 lbuf[3][4][TN_D / 4];  // 48 KB: [buf][col][i/4]
    __shared__ float4 vbuf[2][TN_D / 4];     // 8 KB
    __shared__ float red[4];

    const int tid = threadIdx.x;
    const int w = tid >> 6;
    const int l = tid & 63;
    const bool is_loader = (w >= 4);
    const int c = is_loader ? (w - 4) : w;
    const int j = blockIdx.x * 4 + c;

    // loader register pipeline
    float4 cur0, cur1, cur2, cur3;
    if (is_loader) {
        // prologue: col for step 0, synchronous into lbuf[0]
        if (TR) {
            const float4* mp = (const float4*)(mat + ((size_t)x[0] * TN_D + j) * TN_D);
            float4 a0 = mp[l], a1 = mp[l + 64], a2 = mp[l + 128], a3 = mp[l + 192];
            float4* lb = (float4*)lbuf[0][c];
            lb[l] = a0; lb[l + 64] = a1; lb[l + 128] = a2; lb[l + 192] = a3;
            // issue col for step 1 into cur
            const float4* mq = (const float4*)(mat + ((size_t)x[1] * TN_D + j) * TN_D);
            cur0 = mq[l]; cur1 = mq[l + 64]; cur2 = mq[l + 128]; cur3 = mq[l + 192];
        } else {
            const float* mp = mat + (size_t)x[0] * TN_D * TN_D + j;
            float4* lb = (float4*)lbuf[0][c];
#pragma unroll
            for (int k = 0; k < 4; ++k) {
                int i = 4 * l + 256 * k;
                lb[l + 64 * k] = make_float4(mp[(size_t)i * TN_D], mp[(size_t)(i + 1) * TN_D],
                                             mp[(size_t)(i + 2) * TN_D], mp[(size_t)(i + 3) * TN_D]);
            }
            const float* mq = mat + (size_t)x[1] * TN_D * TN_D + j;
            int i = 4 * l;
            cur0 = make_float4(mq[(size_t)i * TN_D], mq[(size_t)(i + 1) * TN_D],
                               mq[(size_t)(i + 2) * TN_D], mq[(size_t)(i + 3) * TN_D]);
            i += 256;
            cur1 = make_float4(mq[(size_t)i * TN_D], mq[(size_t)(i + 1) * TN_D],
                               mq[(size_t)(i + 2) * TN_D], mq[(size_t)(i + 3) * TN_D]);
            i += 256;
            cur2 = make_float4(mq[(size_t)i * TN_D], mq[(size_t)(i + 1) * TN_D],
                               mq[(size_t)(i + 2) * TN_D], mq[(size_t)(i + 3) * TN_D]);
            i += 256;
            cur3 = make_float4(mq[(size_t)i * TN_D], mq[(size_t)(i + 1) * TN_D],
                               mq[(size_t)(i + 2) * TN_D], mq[(size_t)(i + 3) * TN_D]);
        }
    }

    int bt = 0;  // t % 3 rotating buffer index
    for (int t = 0; t < TN_F; ++t) {
        const int bn = (bt + 1 == 3) ? 0 : bt + 1;  // (t+1) % 3
        float4 n0, n1, n2, n3;
        if (is_loader) {
            // issue loads for col x[t+2] (clamped; last 2 iters load garbage-but-valid)
            const int tt = (t + 2 < TN_F) ? t + 2 : TN_F - 1;
            if (TR) {
                const float4* mp = (const float4*)(mat + ((size_t)x[tt] * TN_D + j) * TN_D);
                n0 = mp[l]; n1 = mp[l + 64]; n2 = mp[l + 128]; n3 = mp[l + 192];
            } else {
                const float* mp = mat + (size_t)x[tt] * TN_D * TN_D + j;
                int i = 4 * l;
                n0 = make_float4(mp[(size_t)i * TN_D], mp[(size_t)(i + 1) * TN_D],
                                 mp[(size_t)(i + 2) * TN_D], mp[(size_t)(i + 3) * TN_D]);
                i += 256;
                n1 = make_float4(mp[(size_t)i * TN_D], mp[(size_t)(i + 1) * TN_D],
                                 mp[(size_t)(i + 2) * TN_D], mp[(size_t)(i + 3) * TN_D]);
                i += 256;
                n2 = make_float4(mp[(size_t)i * TN_D], mp[(size_t)(i + 1) * TN_D],
                                 mp[(size_t)(i + 2) * TN_D], mp[(size_t)(i + 3) * TN_D]);
                i += 256;
                n3 = make_float4(mp[(size_t)i * TN_D], mp[(size_t)(i + 1) * TN_D],
                                 mp[(size_t)(i + 2) * TN_D], mp[(size_t)(i + 3) * TN_D]);
            }
            // write col x[t+1] (waits only the cur loads; n loads stay in flight)
            if (t + 1 < TN_F) {
                float4* lb = (float4*)lbuf[bn][c];
                lb[l] = cur0; lb[l + 64] = cur1; lb[l + 128] = cur2; lb[l + 192] = cur3;
            }
        } else {
            // compute wave: pull v_t into LDS (only poll loads in this wave's vmcnt queue)
            if (t == 0) {
                vbuf[0][tid] = ((const float4*)left)[tid];
            } else {
                vbuf[t & 1][tid] =
                    poll4((const uint32_t*)vg + (size_t)(t - 1) * TN_D + 4 * tid);
            }
        }
        __syncthreads();
        if (is_loader) {
            cur0 = n0; cur1 = n1; cur2 = n2; cur3 = n3;
        } else {
            const float4* mv = (const float4*)lbuf[bt][c];
            const float4* vv = (const float4*)vbuf[t & 1];
            float acc = dot4(vv[l], mv[l]) + dot4(vv[l + 64], mv[l + 64]) +
                        dot4(vv[l + 128], mv[l + 128]) + dot4(vv[l + 192], mv[l + 192]);
#pragma unroll
            for (int off = 32; off; off >>= 1) acc += __shfl_down(acc, off, 64);
            if (l == 0)
                __hip_atomic_store((uint32_t*)vg + (size_t)t * TN_D + j,
                                   __float_as_uint(acc), __ATOMIC_RELAXED,
                                   __HIP_MEMORY_SCOPE_AGENT);
        }
        bt = bn;
    }

    // ---- final dot with right boundary: block 0 ----
    if (blockIdx.x == 0) {
        if (!is_loader) {
            float4 v = poll4((const uint32_t*)vg + (size_t)(TN_F - 1) * TN_D + 4 * tid);
            float p = dot4(v, ((const float4*)right)[tid]);
#pragma unroll
            for (int off = 32; off; off >>= 1) p += __shfl_down(p, off, 64);
            if (l == 0) red[w] = p;
        }
        __syncthreads();
        if (tid == 0) out[0] = red[0] + red[1] + red[2] + red[3];
    }
}

extern "C" void kernel_launch(void* const* d_in, const int* in_sizes, int n_in,
                              void* d_out, int out_size, void* d_ws, size_t ws_size,
                              hipStream_t stream) {
    const int* x = (const int*)d_in[0];
    const float* core = (const float*)d_in[1];
    const float* left = (const float*)d_in[2];
    const float* right = (const float*)d_in[3];
    float* out = (float*)d_out;

    const int nsym = in_sizes[1] / (TN_D * TN_D);
    const size_t coreBytes = (size_t)in_sizes[1] * sizeof(float);
    const size_t vbufBytes = (size_t)TN_F * TN_D * sizeof(float);

    if (ws_size >= coreBytes + vbufBytes) {
        float* coreT = (float*)d_ws;
        float* vg = (float*)((char*)d_ws + coreBytes);
        hipMemsetAsync(vg, 0xAA, vbufBytes, stream);
        tn_transpose<<<dim3(16, 16, nsym), dim3(16, 16), 0, stream>>>(core, coreT);
        tn_chain<true><<<256, 512, 0, stream>>>(x, coreT, left, right, vg, out);
    } else {
        float* vg = (float*)d_ws;
        hipMemsetAsync(vg, 0xAA, vbufBytes, stream);
        tn_chain<false><<<256, 512, 0, stream>>>(x, core, left, right, vg, out);
    }
}